// Round 4
// baseline (1929.218 us; speedup 1.0000x reference)
//
#include <hip/hip_runtime.h>
#include <hip/hip_bf16.h>
#include <math.h>

// Problem constants
#define N_      4
#define L_      256
#define M_      2
#define D_      768
#define H_      12
#define FF_     3072
#define DH_     64
#define LAYERS_ 4
#define BASE_   8          // N*M
#define T_      1032       // BASE_ + N*L
#define TP_     1088       // T_ padded to multiple of 64
#define KK_     258        // M + L
#define QS_     2304       // fused q|k|v row stride
#define PS_     264        // P LDS row stride (bf16)

typedef __bf16 bf16x8 __attribute__((ext_vector_type(8)));
typedef float  f32x4  __attribute__((ext_vector_type(4)));

// Preprocess segment map
#define PP_QKV_END_ 6912
#define PP_W1_END_  16128
#define PP_W2_END_  25344
#define PP_B_END_   25380
#define PP_TOTAL_   26412

struct __align__(16) SharedU {
  union {
    struct { __hip_bfloat16 As[2][4][64][32]; __hip_bfloat16 Bs[2][4][64][32]; } g;
    __hip_bfloat16 Ps[64][PS_];
    float tile[32][33];
  } u;
  float sred[4];
  float sbc;
};

struct KP {
  const int* ids; const float* memory; const float* emb; const float* pos;
  const float* Wq; const float* bq; const float* Wk; const float* bk;
  const float* Wv; const float* bv; const float* W1; const float* b1;
  const float* W2; const float* b2; const float* g1; const float* be1;
  const float* g2; const float* be2;
  float *x, *cb, *bqkv;
  __hip_bfloat16 *xb, *qkvb, *vtb, *hbb, *Wqkvt, *W1t, *W2t;
  float* out;
  unsigned* bar;   // [64*16] spread counters, then release word at +1024
  unsigned nblk;
};

__device__ __forceinline__ void async_load16(const __hip_bfloat16* g, __hip_bfloat16* l) {
  __builtin_amdgcn_global_load_lds(
      (const __attribute__((address_space(1))) unsigned int*)g,
      (__attribute__((address_space(3))) unsigned int*)l, 16, 0, 0);
}

// ---------------------------------------------------------------------------
// Grid barrier: spread arrival counters (64 lines), block 0 aggregates and
// releases. Monotonic counters (no reset within a launch); device-scope
// atomics + __threadfence for cross-XCD visibility.
// ---------------------------------------------------------------------------
__device__ __forceinline__ void gbar(const KP& p, unsigned& idx) {
  __syncthreads();
  __threadfence();   // release: my phase's writes visible device-wide
  if (threadIdx.x == 0) {
    const unsigned tgt = idx + 1;
    __hip_atomic_fetch_add(p.bar + (blockIdx.x & 63) * 16, 1u,
                           __ATOMIC_RELAXED, __HIP_MEMORY_SCOPE_AGENT);
    unsigned* rel = p.bar + 64 * 16;
    if (blockIdx.x == 0) {
      unsigned sum;
      do {
        sum = 0;
        #pragma unroll
        for (int i = 0; i < 64; ++i)
          sum += __hip_atomic_load(p.bar + i * 16, __ATOMIC_RELAXED,
                                   __HIP_MEMORY_SCOPE_AGENT);
      } while (sum < tgt * p.nblk);
      __hip_atomic_store(rel, tgt, __ATOMIC_RELAXED, __HIP_MEMORY_SCOPE_AGENT);
    } else {
      while (__hip_atomic_load(rel, __ATOMIC_RELAXED, __HIP_MEMORY_SCOPE_AGENT) < tgt)
        __builtin_amdgcn_s_sleep(1);
    }
  }
  __syncthreads();
  __threadfence();   // acquire: invalidate caches before reading others' data
  idx++;
}

// ---------------------------------------------------------------------------
// Phase bodies (shared between mega kernel and fallback wrappers)
// ---------------------------------------------------------------------------
__device__ __forceinline__ void pp_unit(int bid, const KP& p, SharedU& sh) {
  const int tid = threadIdx.x;
  const float* src;
  __hip_bfloat16* dst;
  int K, N, bx, by;

  if (bid < PP_QKV_END_) {
    int l = bid / 1728, r = bid - l * 1728;
    int which = r / 576; r -= which * 576;
    by = r / 24; bx = r - by * 24;
    src = (which == 0 ? p.Wq : which == 1 ? p.Wk : p.Wv) + (size_t)l * D_ * D_;
    dst = p.Wqkvt + (size_t)l * QS_ * D_ + (size_t)which * D_ * D_;
    K = D_; N = D_;
  } else if (bid < PP_W1_END_) {
    int r0 = bid - PP_QKV_END_;
    int l = r0 / 2304, r = r0 - l * 2304;
    by = r / 96; bx = r - by * 96;
    src = p.W1 + (size_t)l * D_ * FF_;
    dst = p.W1t + (size_t)l * FF_ * D_;
    K = D_; N = FF_;
  } else if (bid < PP_W2_END_) {
    int r0 = bid - PP_W1_END_;
    int l = r0 / 2304, r = r0 - l * 2304;
    by = r / 24; bx = r - by * 24;
    src = p.W2 + (size_t)l * FF_ * D_;
    dst = p.W2t + (size_t)l * D_ * FF_;
    K = FF_; N = D_;
  } else if (bid < PP_B_END_) {
    int i = (bid - PP_W2_END_) * 256 + tid;
    int l = i / QS_, j = i - l * QS_;
    float v;
    if (j < D_)            v = p.bq[l * D_ + j];
    else if (j < 2 * D_)   v = p.bk[l * D_ + (j - D_)];
    else                   v = p.bv[l * D_ + (j - 2 * D_)];
    p.bqkv[i] = v;
    return;
  } else {
    int row = bid - PP_B_END_;
    const float *s2, *pp;
    if (row < BASE_) {
      s2 = p.memory + (long long)row * D_;
      pp = p.pos + (row & 1) * D_;
    } else {
      int i = row - BASE_;
      int tok = p.ids[i];
      s2 = p.emb + (long long)tok * D_;
      pp = p.pos + (M_ + (i & (L_ - 1))) * D_;
    }
    for (int d = tid; d < D_; d += 256) {
      float v = s2[d] + pp[d];
      p.x[(long long)row * D_ + d]  = v;
      p.xb[(long long)row * D_ + d] = __float2bfloat16(v);
    }
    return;
  }

  const int k0 = by * 32, n0 = bx * 32;
  const int r = tid >> 5, c = tid & 31;
  #pragma unroll
  for (int i = 0; i < 4; ++i)
    sh.u.tile[r + i * 8][c] = src[(size_t)(k0 + r + i * 8) * N + n0 + c];
  __syncthreads();
  #pragma unroll
  for (int i = 0; i < 4; ++i)
    dst[(size_t)(n0 + r + i * 8) * K + k0 + c] = __float2bfloat16(sh.u.tile[c][r + i * 8]);
  __syncthreads();   // tile reuse across stride-loop iterations
}

// 64x64 tile, BK=128, 4 waves 2x2, double-buffered LDS.
template <int ACT, int WF32, int WBF16, int WVT, int NSPLIT>
__device__ __forceinline__ void gemm_tile(
    int bx, int by, int bz,
    const __hip_bfloat16* __restrict__ A, const __hip_bfloat16* __restrict__ Bt,
    const float* __restrict__ bias, float* __restrict__ C,
    __hip_bfloat16* __restrict__ Cb, __hip_bfloat16* __restrict__ vt,
    int N, int Ktot, SharedU& sh) {
  const int tid  = threadIdx.x;
  const int lane = tid & 63, wid = tid >> 6;
  const int ln   = lane & 15, qd = lane >> 4;
  const int wm   = wid >> 1, wn = wid & 1;

  const int K = Ktot / NSPLIT;
  const size_t koff = (size_t)bz * K;
  const size_t arow = (size_t)(by * 64 + wid * 16 + (lane >> 2)) * Ktot + koff + (lane & 3) * 8;
  const size_t brow = (size_t)(bx * 64 + wid * 16 + (lane >> 2)) * Ktot + koff + (lane & 3) * 8;

  f32x4 acc[2][2] = {};

#define STAGE_(b, k0)                                                          \
  do {                                                                         \
    _Pragma("unroll")                                                          \
    for (int s_ = 0; s_ < 4; ++s_) {                                           \
      async_load16(A  + arow + (k0) + s_ * 32, &sh.u.g.As[b][s_][wid * 16][0]);\
      async_load16(Bt + brow + (k0) + s_ * 32, &sh.u.g.Bs[b][s_][wid * 16][0]);\
    }                                                                          \
  } while (0)

  STAGE_(0, 0);
  __syncthreads();
  int buf = 0;
  for (int k0 = 0; k0 < K; k0 += 128) {
    if (k0 + 128 < K) STAGE_(buf ^ 1, k0 + 128);
    #pragma unroll
    for (int s = 0; s < 4; ++s) {
      bf16x8 a0 = *(const bf16x8*)&sh.u.g.As[buf][s][wm * 32 + ln][qd * 8];
      bf16x8 a1 = *(const bf16x8*)&sh.u.g.As[buf][s][wm * 32 + 16 + ln][qd * 8];
      bf16x8 b0 = *(const bf16x8*)&sh.u.g.Bs[buf][s][wn * 32 + ln][qd * 8];
      bf16x8 b1 = *(const bf16x8*)&sh.u.g.Bs[buf][s][wn * 32 + 16 + ln][qd * 8];
      acc[0][0] = __builtin_amdgcn_mfma_f32_16x16x32_bf16(a0, b0, acc[0][0], 0, 0, 0);
      acc[0][1] = __builtin_amdgcn_mfma_f32_16x16x32_bf16(a0, b1, acc[0][1], 0, 0, 0);
      acc[1][0] = __builtin_amdgcn_mfma_f32_16x16x32_bf16(a1, b0, acc[1][0], 0, 0, 0);
      acc[1][1] = __builtin_amdgcn_mfma_f32_16x16x32_bf16(a1, b1, acc[1][1], 0, 0, 0);
    }
    __syncthreads();   // drains vmcnt: next tile landed; buf safe to overwrite
    buf ^= 1;
  }
#undef STAGE_

  #pragma unroll
  for (int mt = 0; mt < 2; ++mt) {
    #pragma unroll
    for (int nt = 0; nt < 2; ++nt) {
      const int col = bx * 64 + wn * 32 + nt * 16 + ln;
      const float bv = (NSPLIT == 1 || bz == 0) ? bias[col] : 0.f;
      #pragma unroll
      for (int i = 0; i < 4; ++i) {
        const int row = by * 64 + wm * 32 + mt * 16 + qd * 4 + i;
        float v = acc[mt][nt][i] + bv;
        if (ACT) v = 0.5f * v * (1.f + erff(v * 0.70710678118654752f));
        if (WF32)
          C[(size_t)bz * TP_ * N + (size_t)row * N + col] = v;
        if (WVT) {
          if (col < 2 * D_) Cb[(size_t)row * N + col] = __float2bfloat16(v);
          else              vt[(size_t)(col - 2 * D_) * TP_ + row] = __float2bfloat16(v);
        } else if (WBF16) {
          Cb[(size_t)row * N + col] = __float2bfloat16(v);
        }
      }
    }
  }
}

// MFMA attention unit (one q-tile x head x batch). No __syncthreads inside:
// Ps rows are wave-private.
__device__ __forceinline__ void attn_unit(int qt, int h, int b, const KP& p, SharedU& sh) {
  const __hip_bfloat16* qkv = p.qkvb;
  const __hip_bfloat16* vtb = p.vtb;
  float* ctx = p.cb;
  const int tid = threadIdx.x;
  const int w = tid >> 6, lane = tid & 63, ln = lane & 15, qd = lane >> 4;

  bf16x8 aq0, aq1;
  {
    int j = qt * 64 + w * 16 + ln;
    int tok = (j < 256) ? (BASE_ + b * L_ + j)
            : ((j < KK_) ? (b * M_ + (j - 256)) : (b * M_));
    const __hip_bfloat16* qp = qkv + (size_t)tok * QS_ + h * DH_ + qd * 8;
    aq0 = *(const bf16x8*)qp;
    aq1 = *(const bf16x8*)(qp + 32);
  }

  f32x4 sa[17];
  #pragma unroll
  for (int nt = 0; nt < 17; ++nt) sa[nt] = (f32x4){0.f, 0.f, 0.f, 0.f};
  #pragma unroll
  for (int nt = 0; nt < 17; ++nt) {
    int key = nt * 16 + ln;
    int ktok = (key < 256) ? (BASE_ + b * L_ + key)
             : ((key < KK_) ? (b * M_ + (key - 256)) : (b * M_));
    const __hip_bfloat16* kp = qkv + (size_t)ktok * QS_ + D_ + h * DH_ + qd * 8;
    bf16x8 b0 = *(const bf16x8*)kp;
    bf16x8 b1 = *(const bf16x8*)(kp + 32);
    sa[nt] = __builtin_amdgcn_mfma_f32_16x16x32_bf16(aq0, b0, sa[nt], 0, 0, 0);
    sa[nt] = __builtin_amdgcn_mfma_f32_16x16x32_bf16(aq1, b1, sa[nt], 0, 0, 0);
  }

  #pragma unroll
  for (int i = 0; i < 4; ++i) {
    float v[17];
    #pragma unroll
    for (int nt = 0; nt < 17; ++nt) v[nt] = sa[nt][i] * 0.125f;
    float mx = -1e30f;
    #pragma unroll
    for (int nt = 0; nt < 16; ++nt) mx = fmaxf(mx, v[nt]);
    if (ln < 2) mx = fmaxf(mx, v[16]);
    #pragma unroll
    for (int m = 1; m < 16; m <<= 1) mx = fmaxf(mx, __shfl_xor(mx, m));
    float sum = 0.f;
    #pragma unroll
    for (int nt = 0; nt < 17; ++nt) {
      float e = (nt == 16 && ln >= 2) ? 0.f : __expf(v[nt] - mx);
      v[nt] = e;
      sum += e;
    }
    #pragma unroll
    for (int m = 1; m < 16; m <<= 1) sum += __shfl_xor(sum, m);
    float is = 1.f / sum;
    const int row = w * 16 + qd * 4 + i;
    #pragma unroll
    for (int nt = 0; nt < 17; ++nt)
      if (nt < 16 || ln < 2)
        sh.u.Ps[row][nt * 16 + ln] = __float2bfloat16(v[nt] * is);
  }

  f32x4 oa[4] = {};
  #pragma unroll
  for (int k0 = 0; k0 < 8; ++k0) {
    bf16x8 ap = *(const bf16x8*)&sh.u.Ps[w * 16 + ln][k0 * 32 + qd * 8];
    #pragma unroll
    for (int nt = 0; nt < 4; ++nt) {
      const __hip_bfloat16* vp = vtb + (size_t)(h * DH_ + nt * 16 + ln) * TP_
                               + BASE_ + b * L_ + k0 * 32 + qd * 8;
      bf16x8 bv = *(const bf16x8*)vp;
      oa[nt] = __builtin_amdgcn_mfma_f32_16x16x32_bf16(ap, bv, oa[nt], 0, 0, 0);
    }
  }
  {
    float p0[4], p1[4];
    #pragma unroll
    for (int i = 0; i < 4; ++i) {
      p0[i] = __bfloat162float(sh.u.Ps[w * 16 + qd * 4 + i][256]);
      p1[i] = __bfloat162float(sh.u.Ps[w * 16 + qd * 4 + i][257]);
    }
    #pragma unroll
    for (int nt = 0; nt < 4; ++nt) {
      const __hip_bfloat16* vp = vtb + (size_t)(h * DH_ + nt * 16 + ln) * TP_ + b * M_;
      float v0 = __bfloat162float(vp[0]);
      float v1 = __bfloat162float(vp[1]);
      #pragma unroll
      for (int i = 0; i < 4; ++i) oa[nt][i] += p0[i] * v0 + p1[i] * v1;
    }
  }

  #pragma unroll
  for (int i = 0; i < 4; ++i) {
    int j = qt * 64 + w * 16 + qd * 4 + i;
    if (j < KK_) {
      int tok = (j < 256) ? (BASE_ + b * L_ + j) : (b * M_ + (j - 256));
      #pragma unroll
      for (int nt = 0; nt < 4; ++nt)
        ctx[(size_t)tok * D_ + h * DH_ + nt * 16 + ln] = oa[nt][i];
    }
  }
}

// x = LN(x + sum_s cb_s); bf16 copy; optionally final output rows.
template <int NS>
__device__ __forceinline__ void ln_row(
    int t, const KP& p, const float* __restrict__ g, const float* __restrict__ b,
    float* __restrict__ out, SharedU& sh) {
  const int tid = threadIdx.x;
  float y[3];
  float s = 0.f;
  #pragma unroll
  for (int i = 0; i < 3; ++i) {
    int d = tid + i * 256;
    float v = p.x[(long long)t * D_ + d];
    #pragma unroll
    for (int s2 = 0; s2 < NS; ++s2)
      v += p.cb[(size_t)s2 * TP_ * D_ + (long long)t * D_ + d];
    y[i] = v;
    s += v;
  }
  #pragma unroll
  for (int o = 32; o > 0; o >>= 1) s += __shfl_down(s, o);
  if ((tid & 63) == 0) sh.sred[tid >> 6] = s;
  __syncthreads();
  if (tid == 0) sh.sbc = (sh.sred[0] + sh.sred[1] + sh.sred[2] + sh.sred[3]) * (1.f / D_);
  __syncthreads();
  const float mu = sh.sbc;
  __syncthreads();
  float vs = 0.f;
  #pragma unroll
  for (int i = 0; i < 3; ++i) { float d = y[i] - mu; vs += d * d; }
  #pragma unroll
  for (int o = 32; o > 0; o >>= 1) vs += __shfl_down(vs, o);
  if ((tid & 63) == 0) sh.sred[tid >> 6] = vs;
  __syncthreads();
  if (tid == 0) sh.sbc = (sh.sred[0] + sh.sred[1] + sh.sred[2] + sh.sred[3]) * (1.f / D_);
  __syncthreads();
  const float inv = rsqrtf(sh.sbc + 1e-5f);
  #pragma unroll
  for (int i = 0; i < 3; ++i) {
    int d = tid + i * 256;
    float v = (y[i] - mu) * inv * g[d] + b[d];
    p.x[(long long)t * D_ + d]  = v;
    p.xb[(long long)t * D_ + d] = __float2bfloat16(v);
    if (out != nullptr && t >= BASE_)
      out[(size_t)(t - BASE_) * D_ + d] = v;
  }
}

// ---------------------------------------------------------------------------
// The persistent cooperative mega-kernel.
// ---------------------------------------------------------------------------
__global__ __launch_bounds__(256, 2) void encoder_mega(KP p) {
  __shared__ SharedU sh;
  unsigned bidx = 0;
  const unsigned nb = p.nblk;

  for (unsigned u = blockIdx.x; u < PP_TOTAL_; u += nb) pp_unit((int)u, p, sh);
  gbar(p, bidx);

  for (int l = 0; l < LAYERS_; ++l) {
    const __hip_bfloat16* Wt = p.Wqkvt + (size_t)l * QS_ * D_;
    for (unsigned u = blockIdx.x; u < 36u * 17u; u += nb)
      gemm_tile<0, 0, 1, 1, 1>((int)(u % 36u), (int)(u / 36u), 0,
                               p.xb, Wt, p.bqkv + l * QS_, nullptr, p.qkvb, p.vtb,
                               QS_, D_, sh);
    gbar(p, bidx);

    for (unsigned u = blockIdx.x; u < 240u; u += nb)
      attn_unit((int)(u % 5u), (int)((u / 5u) % 12u), (int)(u / 60u), p, sh);
    gbar(p, bidx);

    for (unsigned u = blockIdx.x; u < (unsigned)T_; u += nb)
      ln_row<1>((int)u, p, p.g1 + l * D_, p.be1 + l * D_, nullptr, sh);
    gbar(p, bidx);

    for (unsigned u = blockIdx.x; u < 48u * 17u; u += nb)
      gemm_tile<1, 0, 1, 0, 1>((int)(u % 48u), (int)(u / 48u), 0,
                               p.xb, p.W1t + (size_t)l * FF_ * D_, p.b1 + l * FF_,
                               nullptr, p.hbb, nullptr, FF_, D_, sh);
    gbar(p, bidx);

    for (unsigned u = blockIdx.x; u < 2u * 204u; u += nb) {
      unsigned z = u / 204u, r = u % 204u;
      gemm_tile<0, 1, 0, 0, 2>((int)(r % 12u), (int)(r / 12u), (int)z,
                               p.hbb, p.W2t + (size_t)l * D_ * FF_, p.b2 + l * D_,
                               p.cb, nullptr, nullptr, D_, FF_, sh);
    }
    gbar(p, bidx);

    for (unsigned u = blockIdx.x; u < (unsigned)T_; u += nb)
      ln_row<2>((int)u, p, p.g2 + l * D_, p.be2 + l * D_,
                (l == LAYERS_ - 1) ? p.out : nullptr, sh);
    if (l != LAYERS_ - 1) gbar(p, bidx);
  }
}

// ---------------------------------------------------------------------------
// Fallback wrappers (R3 multi-dispatch path) — used only if cooperative
// launch is rejected.
// ---------------------------------------------------------------------------
__global__ __launch_bounds__(256) void pp_k(KP p) {
  __shared__ SharedU sh;
  pp_unit((int)blockIdx.x, p, sh);
}
__global__ __launch_bounds__(256) void gemm_qkv_k(KP p, int l) {
  __shared__ SharedU sh;
  gemm_tile<0, 0, 1, 1, 1>(blockIdx.x, blockIdx.y, 0, p.xb,
                           p.Wqkvt + (size_t)l * QS_ * D_, p.bqkv + l * QS_,
                           nullptr, p.qkvb, p.vtb, QS_, D_, sh);
}
__global__ __launch_bounds__(256) void gemm_ffn1_k(KP p, int l) {
  __shared__ SharedU sh;
  gemm_tile<1, 0, 1, 0, 1>(blockIdx.x, blockIdx.y, 0, p.xb,
                           p.W1t + (size_t)l * FF_ * D_, p.b1 + l * FF_,
                           nullptr, p.hbb, nullptr, FF_, D_, sh);
}
__global__ __launch_bounds__(256) void gemm_ffn2_k(KP p, int l) {
  __shared__ SharedU sh;
  gemm_tile<0, 1, 0, 0, 2>(blockIdx.x, blockIdx.y, blockIdx.z, p.hbb,
                           p.W2t + (size_t)l * D_ * FF_, p.b2 + l * D_,
                           p.cb, nullptr, nullptr, D_, FF_, sh);
}
__global__ __launch_bounds__(256) void attn_k(KP p) {
  __shared__ SharedU sh;
  attn_unit(blockIdx.x, blockIdx.y, blockIdx.z, p, sh);
}
__global__ __launch_bounds__(256) void ln1_k(KP p, int l) {
  __shared__ SharedU sh;
  ln_row<1>((int)blockIdx.x, p, p.g1 + l * D_, p.be1 + l * D_, nullptr, sh);
}
__global__ __launch_bounds__(256) void ln2_k(KP p, int l) {
  __shared__ SharedU sh;
  ln_row<2>((int)blockIdx.x, p, p.g2 + l * D_, p.be2 + l * D_,
            (l == LAYERS_ - 1) ? p.out : nullptr, sh);
}

// ---------------------------------------------------------------------------
extern "C" void kernel_launch(void* const* d_in, const int* in_sizes, int n_in,
                              void* d_out, int out_size, void* d_ws, size_t ws_size,
                              hipStream_t stream) {
  KP p;
  p.ids    = (const int*)  d_in[0];
  p.memory = (const float*)d_in[1];
  p.emb    = (const float*)d_in[2];
  p.pos    = (const float*)d_in[3];
  p.Wq     = (const float*)d_in[4];
  p.bq     = (const float*)d_in[5];
  p.Wk     = (const float*)d_in[6];
  p.bk     = (const float*)d_in[7];
  p.Wv     = (const float*)d_in[8];
  p.bv     = (const float*)d_in[9];
  p.W1     = (const float*)d_in[10];
  p.b1     = (const float*)d_in[11];
  p.W2     = (const float*)d_in[12];
  p.b2     = (const float*)d_in[13];
  p.g1     = (const float*)d_in[14];
  p.be1    = (const float*)d_in[15];
  p.g2     = (const float*)d_in[16];
  p.be2    = (const float*)d_in[17];
  p.out    = (float*)d_out;

  char* w = (char*)d_ws;
  p.bar   = (unsigned*)w;                  w += 8192;
  p.x     = (float*)w;                     w += (size_t)TP_ * D_ * 4;
  p.cb    = (float*)w;                     w += (size_t)2 * TP_ * D_ * 4;
  p.bqkv  = (float*)w;                     w += (size_t)LAYERS_ * QS_ * 4;
  p.xb    = (__hip_bfloat16*)w;            w += (size_t)TP_ * D_ * 2;
  p.qkvb  = (__hip_bfloat16*)w;            w += (size_t)TP_ * QS_ * 2;
  p.vtb   = (__hip_bfloat16*)w;            w += (size_t)D_ * TP_ * 2;
  p.hbb   = (__hip_bfloat16*)w;            w += (size_t)TP_ * FF_ * 2;
  p.Wqkvt = (__hip_bfloat16*)w;            w += (size_t)LAYERS_ * QS_ * D_ * 2;
  p.W1t   = (__hip_bfloat16*)w;            w += (size_t)LAYERS_ * FF_ * D_ * 2;
  p.W2t   = (__hip_bfloat16*)w;            w += (size_t)LAYERS_ * D_ * FF_ * 2;

  static int nbs = 0;
  if (nbs == 0) {
    int nb = 0;
    if (hipOccupancyMaxActiveBlocksPerMultiprocessor(
            &nb, (const void*)encoder_mega, 256, 0) != hipSuccess || nb < 1)
      nb = 1;
    if (nb > 4) nb = 4;
    nbs = nb * 256;
  }
  p.nblk = (unsigned)nbs;

  hipMemsetAsync(p.bar, 0, 8192, stream);
  void* args[] = { &p };
  hipError_t err = hipLaunchCooperativeKernel(
      (const void*)encoder_mega, dim3((unsigned)nbs), dim3(256), args, 0, stream);

  if (err != hipSuccess) {
    // Fallback: proven multi-dispatch path.
    pp_k<<<PP_TOTAL_, 256, 0, stream>>>(p);
    for (int i = 0; i < LAYERS_; ++i) {
      gemm_qkv_k<<<dim3(QS_ / 64, TP_ / 64), 256, 0, stream>>>(p, i);
      attn_k<<<dim3(5, H_, N_), 256, 0, stream>>>(p);
      ln1_k<<<T_, 256, 0, stream>>>(p, i);
      gemm_ffn1_k<<<dim3(FF_ / 64, TP_ / 64), 256, 0, stream>>>(p, i);
      gemm_ffn2_k<<<dim3(D_ / 64, TP_ / 64, 2), 256, 0, stream>>>(p, i);
      ln2_k<<<T_, 256, 0, stream>>>(p, i);
    }
  }
}

// Round 5
// 519.334 us; speedup vs baseline: 3.7148x; 3.7148x over previous
//
#include <hip/hip_runtime.h>
#include <hip/hip_bf16.h>
#include <math.h>

// Problem constants
#define N_      4
#define L_      256
#define M_      2
#define D_      768
#define H_      12
#define FF_     3072
#define DH_     64
#define LAYERS_ 4
#define BASE_   8          // N*M
#define T_      1032       // BASE_ + N*L
#define TP_     1088       // T_ padded to multiple of 64
#define KK_     258        // M + L
#define QS_     2304       // fused q|k|v row stride
#define PS_     264        // P LDS row stride (bf16)

typedef __bf16 bf16x8 __attribute__((ext_vector_type(8)));
typedef float  f32x4  __attribute__((ext_vector_type(4)));

// Preprocess id space (per-layer-major weights, then bias, then embed)
#define PPL_      6336     // per-layer: 1728 qkv + 2304 w1 + 2304 w2
#define PP_WEND_  25344    // 4*PPL_
#define PP_B_END_ 25380
#define PP_TOTAL_ 26412
#define PP_UP_    7404     // upfront: PPL_ (layer 0) + 1068 (bias+embed)

struct KP {
  const int* ids; const float* memory; const float* emb; const float* pos;
  const float* Wq; const float* bq; const float* Wk; const float* bk;
  const float* Wv; const float* bv; const float* W1; const float* b1;
  const float* W2; const float* b2; const float* g1; const float* be1;
  const float* g2; const float* be2;
  float *x, *cb, *bqkv;
  __hip_bfloat16 *xb, *qkvb, *vtb, *hbb, *Wqkvt, *W1t, *W2t;
  float* out;
};

struct __align__(16) SharedG {   // 32 KB: dbuf BK=64
  __hip_bfloat16 As[2][2][64][32];
  __hip_bfloat16 Bs[2][2][64][32];
};

__device__ __forceinline__ void async_load16(const __hip_bfloat16* g, __hip_bfloat16* l) {
  __builtin_amdgcn_global_load_lds(
      (const __attribute__((address_space(1))) unsigned int*)g,
      (__attribute__((address_space(3))) unsigned int*)l, 16, 0, 0);
}

// ---------------------------------------------------------------------------
// One preprocess unit (weight transpose tile / bias pack / embed row).
// ---------------------------------------------------------------------------
__device__ __forceinline__ void pp_unit(int bid, const KP& p, float (&tile)[32][33]) {
  const int tid = threadIdx.x;
  const float* src;
  __hip_bfloat16* dst;
  int K, N, bx, by;

  if (bid < PP_WEND_) {
    int l = bid / PPL_, r = bid - l * PPL_;
    if (r < 1728) {
      int which = r / 576, t = r - which * 576;
      by = t / 24; bx = t - by * 24;
      src = (which == 0 ? p.Wq : which == 1 ? p.Wk : p.Wv) + (size_t)l * D_ * D_;
      dst = p.Wqkvt + (size_t)l * QS_ * D_ + (size_t)which * D_ * D_;
      K = D_; N = D_;
    } else if (r < 4032) {
      int t = r - 1728;
      by = t / 96; bx = t - by * 96;
      src = p.W1 + (size_t)l * D_ * FF_;
      dst = p.W1t + (size_t)l * FF_ * D_;
      K = D_; N = FF_;
    } else {
      int t = r - 4032;
      by = t / 24; bx = t - by * 24;
      src = p.W2 + (size_t)l * FF_ * D_;
      dst = p.W2t + (size_t)l * D_ * FF_;
      K = FF_; N = D_;
    }
  } else if (bid < PP_B_END_) {
    int i = (bid - PP_WEND_) * 256 + tid;
    int l = i / QS_, j = i - l * QS_;
    float v;
    if (j < D_)            v = p.bq[l * D_ + j];
    else if (j < 2 * D_)   v = p.bk[l * D_ + (j - D_)];
    else                   v = p.bv[l * D_ + (j - 2 * D_)];
    p.bqkv[i] = v;
    return;
  } else {
    int row = bid - PP_B_END_;
    const float *s2, *pp;
    if (row < BASE_) {
      s2 = p.memory + (long long)row * D_;
      pp = p.pos + (row & 1) * D_;
    } else {
      int i = row - BASE_;
      int tok = p.ids[i];
      s2 = p.emb + (long long)tok * D_;
      pp = p.pos + (M_ + (i & (L_ - 1))) * D_;
    }
    for (int d = tid; d < D_; d += 256) {
      float v = s2[d] + pp[d];
      p.x[(long long)row * D_ + d]  = v;
      p.xb[(long long)row * D_ + d] = __float2bfloat16(v);
    }
    return;
  }

  // 32x32 transpose tile: src[K,N] fp32 -> dst[N,K] bf16
  const int k0 = by * 32, n0 = bx * 32;
  const int r = tid >> 5, c = tid & 31;
  #pragma unroll
  for (int i = 0; i < 4; ++i)
    tile[r + i * 8][c] = src[(size_t)(k0 + r + i * 8) * N + n0 + c];
  __syncthreads();
  #pragma unroll
  for (int i = 0; i < 4; ++i)
    dst[(size_t)(n0 + r + i * 8) * K + k0 + c] = __float2bfloat16(tile[c][r + i * 8]);
}

// ---------------------------------------------------------------------------
// 64x64 tile GEMM, BK=64, 4 waves 2x2, double-buffered 32 KB LDS.
// NSPLIT: K split across bz; fp32 partials at C + bz*TP_*N, bias by split 0.
// WVT: cols>=1536 go transposed to vt[col-1536][row].
// ---------------------------------------------------------------------------
template <int ACT, int WF32, int WBF16, int WVT, int NSPLIT>
__device__ __forceinline__ void gemm_tile(
    int bx, int by, int bz,
    const __hip_bfloat16* __restrict__ A, const __hip_bfloat16* __restrict__ Bt,
    const float* __restrict__ bias, float* __restrict__ C,
    __hip_bfloat16* __restrict__ Cb, __hip_bfloat16* __restrict__ vt,
    int N, int Ktot, SharedG& sg) {
  const int tid  = threadIdx.x;
  const int lane = tid & 63, wid = tid >> 6;
  const int ln   = lane & 15, qd = lane >> 4;
  const int wm   = wid >> 1, wn = wid & 1;

  const int K = Ktot / NSPLIT;
  const size_t koff = (size_t)bz * K;
  const size_t arow = (size_t)(by * 64 + wid * 16 + (lane >> 2)) * Ktot + koff + (lane & 3) * 8;
  const size_t brow = (size_t)(bx * 64 + wid * 16 + (lane >> 2)) * Ktot + koff + (lane & 3) * 8;

  f32x4 acc[2][2] = {};

#define STAGE_(b, k0)                                                         \
  do {                                                                        \
    _Pragma("unroll")                                                         \
    for (int s_ = 0; s_ < 2; ++s_) {                                          \
      async_load16(A  + arow + (k0) + s_ * 32, &sg.As[b][s_][wid * 16][0]);   \
      async_load16(Bt + brow + (k0) + s_ * 32, &sg.Bs[b][s_][wid * 16][0]);   \
    }                                                                         \
  } while (0)

  STAGE_(0, 0);
  __syncthreads();
  int buf = 0;
  for (int k0 = 0; k0 < K; k0 += 64) {
    if (k0 + 64 < K) STAGE_(buf ^ 1, k0 + 64);
    #pragma unroll
    for (int s = 0; s < 2; ++s) {
      bf16x8 a0 = *(const bf16x8*)&sg.As[buf][s][wm * 32 + ln][qd * 8];
      bf16x8 a1 = *(const bf16x8*)&sg.As[buf][s][wm * 32 + 16 + ln][qd * 8];
      bf16x8 b0 = *(const bf16x8*)&sg.Bs[buf][s][wn * 32 + ln][qd * 8];
      bf16x8 b1 = *(const bf16x8*)&sg.Bs[buf][s][wn * 32 + 16 + ln][qd * 8];
      acc[0][0] = __builtin_amdgcn_mfma_f32_16x16x32_bf16(a0, b0, acc[0][0], 0, 0, 0);
      acc[0][1] = __builtin_amdgcn_mfma_f32_16x16x32_bf16(a0, b1, acc[0][1], 0, 0, 0);
      acc[1][0] = __builtin_amdgcn_mfma_f32_16x16x32_bf16(a1, b0, acc[1][0], 0, 0, 0);
      acc[1][1] = __builtin_amdgcn_mfma_f32_16x16x32_bf16(a1, b1, acc[1][1], 0, 0, 0);
    }
    __syncthreads();   // drains vmcnt: next tile landed; buf safe to overwrite
    buf ^= 1;
  }
#undef STAGE_

  #pragma unroll
  for (int mt = 0; mt < 2; ++mt) {
    #pragma unroll
    for (int nt = 0; nt < 2; ++nt) {
      const int col = bx * 64 + wn * 32 + nt * 16 + ln;
      const float bv = (NSPLIT == 1 || bz == 0) ? bias[col] : 0.f;
      #pragma unroll
      for (int i = 0; i < 4; ++i) {
        const int row = by * 64 + wm * 32 + mt * 16 + qd * 4 + i;
        float v = acc[mt][nt][i] + bv;
        if (ACT) v = 0.5f * v * (1.f + erff(v * 0.70710678118654752f));
        if (WF32)
          C[(size_t)bz * TP_ * N + (size_t)row * N + col] = v;
        if (WVT) {
          if (col < 2 * D_) Cb[(size_t)row * N + col] = __float2bfloat16(v);
          else              vt[(size_t)(col - 2 * D_) * TP_ + row] = __float2bfloat16(v);
        } else if (WBF16) {
          Cb[(size_t)row * N + col] = __float2bfloat16(v);
        }
      }
    }
  }
}

// ---------------------------------------------------------------------------
// Kernels
// ---------------------------------------------------------------------------
__global__ __launch_bounds__(256) void pp_k(KP p) {
  __shared__ float tile[32][33];
  int bid = blockIdx.x;
  if (bid >= PPL_) bid = bid - PPL_ + PP_WEND_;   // layer-0 weights + bias + embed
  pp_unit(bid, p, tile);
}

__global__ __launch_bounds__(256, 4) void gemm_qkv_k(KP p, int l) {
  __shared__ SharedG sg;
  gemm_tile<0, 0, 1, 1, 1>(blockIdx.x, blockIdx.y, 0, p.xb,
                           p.Wqkvt + (size_t)l * QS_ * D_, p.bqkv + l * QS_,
                           nullptr, p.qkvb, p.vtb, QS_, D_, sg);
}

// FFN1 GEMM with next layer's weight transposes appended as extra blocks.
__global__ __launch_bounds__(256, 4) void gemm_ffn1_k(KP p, int l) {
  __shared__ union { SharedG g; float tile[32][33]; } sh;
  const int bid = blockIdx.x;
  if (bid < 48 * 17) {
    gemm_tile<1, 0, 1, 0, 1>(bid % 48, bid / 48, 0, p.xb,
                             p.W1t + (size_t)l * FF_ * D_, p.b1 + l * FF_,
                             nullptr, p.hbb, nullptr, FF_, D_, sh.g);
  } else {
    pp_unit(bid - 48 * 17 + (l + 1) * PPL_, p, sh.tile);
  }
}

__global__ __launch_bounds__(256, 4) void gemm_ffn2_k(KP p, int l) {
  __shared__ SharedG sg;
  gemm_tile<0, 1, 0, 0, 2>(blockIdx.x, blockIdx.y, blockIdx.z, p.hbb,
                           p.W2t + (size_t)l * D_ * FF_, p.b2 + l * D_,
                           p.cb, nullptr, nullptr, D_, FF_, sg);
}

// ---------------------------------------------------------------------------
// MFMA attention. grid = (5 q-tiles, 12 heads, 4 batches), 4 waves/block.
// ---------------------------------------------------------------------------
__global__ __launch_bounds__(256) void attn_k(KP p) {
  __shared__ __align__(16) __hip_bfloat16 Ps[64][PS_];
  const __hip_bfloat16* qkv = p.qkvb;
  const __hip_bfloat16* vtb = p.vtb;
  float* ctx = p.cb;
  const int qt = blockIdx.x, h = blockIdx.y, b = blockIdx.z;
  const int tid = threadIdx.x;
  const int w = tid >> 6, lane = tid & 63, ln = lane & 15, qd = lane >> 4;

  bf16x8 aq0, aq1;
  {
    int j = qt * 64 + w * 16 + ln;
    int tok = (j < 256) ? (BASE_ + b * L_ + j)
            : ((j < KK_) ? (b * M_ + (j - 256)) : (b * M_));
    const __hip_bfloat16* qp = qkv + (size_t)tok * QS_ + h * DH_ + qd * 8;
    aq0 = *(const bf16x8*)qp;
    aq1 = *(const bf16x8*)(qp + 32);
  }

  f32x4 sa[17];
  #pragma unroll
  for (int nt = 0; nt < 17; ++nt) sa[nt] = (f32x4){0.f, 0.f, 0.f, 0.f};
  #pragma unroll
  for (int nt = 0; nt < 17; ++nt) {
    int key = nt * 16 + ln;
    int ktok = (key < 256) ? (BASE_ + b * L_ + key)
             : ((key < KK_) ? (b * M_ + (key - 256)) : (b * M_));
    const __hip_bfloat16* kp = qkv + (size_t)ktok * QS_ + D_ + h * DH_ + qd * 8;
    bf16x8 b0 = *(const bf16x8*)kp;
    bf16x8 b1 = *(const bf16x8*)(kp + 32);
    sa[nt] = __builtin_amdgcn_mfma_f32_16x16x32_bf16(aq0, b0, sa[nt], 0, 0, 0);
    sa[nt] = __builtin_amdgcn_mfma_f32_16x16x32_bf16(aq1, b1, sa[nt], 0, 0, 0);
  }

  #pragma unroll
  for (int i = 0; i < 4; ++i) {
    float v[17];
    #pragma unroll
    for (int nt = 0; nt < 17; ++nt) v[nt] = sa[nt][i] * 0.125f;
    float mx = -1e30f;
    #pragma unroll
    for (int nt = 0; nt < 16; ++nt) mx = fmaxf(mx, v[nt]);
    if (ln < 2) mx = fmaxf(mx, v[16]);
    #pragma unroll
    for (int m = 1; m < 16; m <<= 1) mx = fmaxf(mx, __shfl_xor(mx, m));
    float sum = 0.f;
    #pragma unroll
    for (int nt = 0; nt < 17; ++nt) {
      float e = (nt == 16 && ln >= 2) ? 0.f : __expf(v[nt] - mx);
      v[nt] = e;
      sum += e;
    }
    #pragma unroll
    for (int m = 1; m < 16; m <<= 1) sum += __shfl_xor(sum, m);
    float is = 1.f / sum;
    const int row = w * 16 + qd * 4 + i;
    #pragma unroll
    for (int nt = 0; nt < 17; ++nt)
      if (nt < 16 || ln < 2)
        Ps[row][nt * 16 + ln] = __float2bfloat16(v[nt] * is);
  }

  f32x4 oa[4] = {};
  #pragma unroll
  for (int k0 = 0; k0 < 8; ++k0) {
    bf16x8 ap = *(const bf16x8*)&Ps[w * 16 + ln][k0 * 32 + qd * 8];
    #pragma unroll
    for (int nt = 0; nt < 4; ++nt) {
      const __hip_bfloat16* vp = vtb + (size_t)(h * DH_ + nt * 16 + ln) * TP_
                               + BASE_ + b * L_ + k0 * 32 + qd * 8;
      bf16x8 bv = *(const bf16x8*)vp;
      oa[nt] = __builtin_amdgcn_mfma_f32_16x16x32_bf16(ap, bv, oa[nt], 0, 0, 0);
    }
  }
  {
    float p0[4], p1[4];
    #pragma unroll
    for (int i = 0; i < 4; ++i) {
      p0[i] = __bfloat162float(Ps[w * 16 + qd * 4 + i][256]);
      p1[i] = __bfloat162float(Ps[w * 16 + qd * 4 + i][257]);
    }
    #pragma unroll
    for (int nt = 0; nt < 4; ++nt) {
      const __hip_bfloat16* vp = vtb + (size_t)(h * DH_ + nt * 16 + ln) * TP_ + b * M_;
      float v0 = __bfloat162float(vp[0]);
      float v1 = __bfloat162float(vp[1]);
      #pragma unroll
      for (int i = 0; i < 4; ++i) oa[nt][i] += p0[i] * v0 + p1[i] * v1;
    }
  }

  #pragma unroll
  for (int i = 0; i < 4; ++i) {
    int j = qt * 64 + w * 16 + qd * 4 + i;
    if (j < KK_) {
      int tok = (j < 256) ? (BASE_ + b * L_ + j) : (b * M_ + (j - 256));
      #pragma unroll
      for (int nt = 0; nt < 4; ++nt)
        ctx[(size_t)tok * D_ + h * DH_ + nt * 16 + ln] = oa[nt][i];
    }
  }
}

// ---------------------------------------------------------------------------
// x = LN(x + sum_s cb_s); bf16 copy; optionally final output rows.
// ---------------------------------------------------------------------------
template <int NS>
__global__ __launch_bounds__(256) void ln_k(KP p, int l, int last) {
  __shared__ float sred[4];
  __shared__ float sbc;
  const float* g = (NS == 1) ? p.g1 + l * D_ : p.g2 + l * D_;
  const float* b = (NS == 1) ? p.be1 + l * D_ : p.be2 + l * D_;
  const int t = blockIdx.x, tid = threadIdx.x;
  float y[3];
  float s = 0.f;
  #pragma unroll
  for (int i = 0; i < 3; ++i) {
    int d = tid + i * 256;
    float v = p.x[(long long)t * D_ + d];
    #pragma unroll
    for (int s2 = 0; s2 < NS; ++s2)
      v += p.cb[(size_t)s2 * TP_ * D_ + (long long)t * D_ + d];
    y[i] = v;
    s += v;
  }
  #pragma unroll
  for (int o = 32; o > 0; o >>= 1) s += __shfl_down(s, o);
  if ((tid & 63) == 0) sred[tid >> 6] = s;
  __syncthreads();
  if (tid == 0) sbc = (sred[0] + sred[1] + sred[2] + sred[3]) * (1.f / D_);
  __syncthreads();
  const float mu = sbc;
  __syncthreads();
  float vs = 0.f;
  #pragma unroll
  for (int i = 0; i < 3; ++i) { float d = y[i] - mu; vs += d * d; }
  #pragma unroll
  for (int o = 32; o > 0; o >>= 1) vs += __shfl_down(vs, o);
  if ((tid & 63) == 0) sred[tid >> 6] = vs;
  __syncthreads();
  if (tid == 0) sbc = (sred[0] + sred[1] + sred[2] + sred[3]) * (1.f / D_);
  __syncthreads();
  const float inv = rsqrtf(sbc + 1e-5f);
  #pragma unroll
  for (int i = 0; i < 3; ++i) {
    int d = tid + i * 256;
    float v = (y[i] - mu) * inv * g[d] + b[d];
    p.x[(long long)t * D_ + d]  = v;
    p.xb[(long long)t * D_ + d] = __float2bfloat16(v);
    if (last && t >= BASE_)
      p.out[(size_t)(t - BASE_) * D_ + d] = v;
  }
}

// ---------------------------------------------------------------------------
extern "C" void kernel_launch(void* const* d_in, const int* in_sizes, int n_in,
                              void* d_out, int out_size, void* d_ws, size_t ws_size,
                              hipStream_t stream) {
  KP p;
  p.ids    = (const int*)  d_in[0];
  p.memory = (const float*)d_in[1];
  p.emb    = (const float*)d_in[2];
  p.pos    = (const float*)d_in[3];
  p.Wq     = (const float*)d_in[4];
  p.bq     = (const float*)d_in[5];
  p.Wk     = (const float*)d_in[6];
  p.bk     = (const float*)d_in[7];
  p.Wv     = (const float*)d_in[8];
  p.bv     = (const float*)d_in[9];
  p.W1     = (const float*)d_in[10];
  p.b1     = (const float*)d_in[11];
  p.W2     = (const float*)d_in[12];
  p.b2     = (const float*)d_in[13];
  p.g1     = (const float*)d_in[14];
  p.be1    = (const float*)d_in[15];
  p.g2     = (const float*)d_in[16];
  p.be2    = (const float*)d_in[17];
  p.out    = (float*)d_out;

  char* w = (char*)d_ws;
  p.x     = (float*)w;                     w += (size_t)TP_ * D_ * 4;
  p.cb    = (float*)w;                     w += (size_t)2 * TP_ * D_ * 4;
  p.bqkv  = (float*)w;                     w += (size_t)LAYERS_ * QS_ * 4;
  p.xb    = (__hip_bfloat16*)w;            w += (size_t)TP_ * D_ * 2;
  p.qkvb  = (__hip_bfloat16*)w;            w += (size_t)TP_ * QS_ * 2;
  p.vtb   = (__hip_bfloat16*)w;            w += (size_t)D_ * TP_ * 2;
  p.hbb   = (__hip_bfloat16*)w;            w += (size_t)TP_ * FF_ * 2;
  p.Wqkvt = (__hip_bfloat16*)w;            w += (size_t)LAYERS_ * QS_ * D_ * 2;
  p.W1t   = (__hip_bfloat16*)w;            w += (size_t)LAYERS_ * FF_ * D_ * 2;
  p.W2t   = (__hip_bfloat16*)w;            w += (size_t)LAYERS_ * D_ * FF_ * 2;

  // Upfront: layer-0 weights + bias pack + embedding only.
  pp_k<<<PP_UP_, 256, 0, stream>>>(p);

  for (int i = 0; i < LAYERS_; ++i) {
    gemm_qkv_k<<<dim3(QS_ / 64, TP_ / 64), 256, 0, stream>>>(p, i);
    attn_k<<<dim3(5, H_, N_), 256, 0, stream>>>(p);
    ln_k<1><<<T_, 256, 0, stream>>>(p, i, 0);
    // FFN1 + (layers 1..3) next layer's weight transposes appended
    gemm_ffn1_k<<<48 * 17 + (i < LAYERS_ - 1 ? PPL_ : 0), 256, 0, stream>>>(p, i);
    gemm_ffn2_k<<<dim3(D_ / 64, TP_ / 64, 2), 256, 0, stream>>>(p, i);
    ln_k<2><<<T_, 256, 0, stream>>>(p, i, i == LAYERS_ - 1 ? 1 : 0);
  }
}